// Round 7
// baseline (189.052 us; speedup 1.0000x reference)
//
#include <hip/hip_runtime.h>

#define IMG_H 480
#define IMG_W 640
#define OUT_H 470    // 480 - 10
#define OUT_W 630    // 640 - 10
#define NBATCH 32
#define SW 118       // output columns per wave (128 input cols - 10 halo)
#define NSTRIPE 6    // ceil(630 / 118)
#define RCH 30       // output rows per wave-chunk
#define NCHUNK 16    // 16 * 30 = 480 >= 470
#define NROWS (RCH + 10)   // 40 input rows per chunk

#define SSIM_C1 1.0f // (0.01*100)^2
#define SSIM_C2 9.0f // (0.03*100)^2

// Normalized 11-tap Gaussian (sigma=1.5), matches numpy fp32 window to ~1e-7 rel.
__device__ constexpr float WG[11] = {
    0.00102838f, 0.00759876f, 0.03600077f, 0.10936068f, 0.21300554f,
    0.26601173f,
    0.21300554f, 0.10936068f, 0.03600077f, 0.00759876f, 0.00102838f
};

// lane+j neighbor fetch via ds_bpermute (register crossbar, no LDS storage,
// no barriers). Wrap for lane+j>63 returns in-wave data (finite), masked by
// the validity predicates.
__device__ __forceinline__ float lane_shift(int baddr, int j, float v) {
    return __int_as_float(
        __builtin_amdgcn_ds_bpermute(baddr + (j << 2), __float_as_int(v)));
}

// One phase of the 11-deep vertical ring, 2 output columns per lane.
// P must be compile-time so acc[] indices and weight selects fold; it ≡ P (mod 11).
// REGISTER BUDGET NOTE (R4/R5 lesson): ring = 110 regs + ~50 working; gfx950
// unified VGPR/AGPR pool ~512/wave -> __launch_bounds__(64,3) gives a 170-reg
// cap. waves/EU > 3 here would spill the ring to scratch (WRITE_SIZE balloons).
#define PHASE(P, IT)                                                          \
  {                                                                           \
    const int it = (IT);                                                      \
    /* prefetch next input row (coalesced float2) to hide VMEM latency */     \
    float2 n1 = make_float2(0.f, 0.f), n2 = n1;                               \
    if (it + 1 < NROWS) {                                                     \
      int gy = y0 + it + 1; if (gy > IMG_H - 1) gy = IMG_H - 1;               \
      n1 = *(const float2*)(p1 + gy * IMG_W + colA);                          \
      n2 = *(const float2*)(p2 + gy * IMG_W + colA);                          \
    }                                                                         \
    /* gather cols 2l..2l+11 (pairs from lanes l..l+5): 20 bpermutes */       \
    float v1[12], v2[12];                                                     \
    v1[0] = c1.x; v1[1] = c1.y; v2[0] = c2.x; v2[1] = c2.y;                   \
    _Pragma("unroll")                                                         \
    for (int j = 1; j <= 5; ++j) {                                            \
      v1[2*j]   = lane_shift(baddr, j, c1.x);                                 \
      v1[2*j+1] = lane_shift(baddr, j, c1.y);                                 \
      v2[2*j]   = lane_shift(baddr, j, c2.x);                                 \
      v2[2*j+1] = lane_shift(baddr, j, c2.y);                                 \
    }                                                                         \
    /* horizontal 11-tap pass, 5 channels, two outputs (A: v[0..10], B: v[1..11]) */ \
    float h1A=0.f,h2A=0.f,h11A=0.f,h22A=0.f,h12A=0.f;                         \
    float h1B=0.f,h2B=0.f,h11B=0.f,h22B=0.f,h12B=0.f;                         \
    _Pragma("unroll")                                                         \
    for (int j = 0; j < 11; ++j) {                                            \
      float a1 = v1[j], a2 = v2[j];                                           \
      float t1 = WG[j] * a1, t2 = WG[j] * a2;                                 \
      h1A += t1; h2A += t2;                                                   \
      h11A = fmaf(t1, a1, h11A);                                              \
      h22A = fmaf(t2, a2, h22A);                                              \
      h12A = fmaf(t1, a2, h12A);                                              \
      float b1 = v1[j+1], b2 = v2[j+1];                                       \
      float u1 = WG[j] * b1, u2 = WG[j] * b2;                                 \
      h1B += u1; h2B += u2;                                                   \
      h11B = fmaf(u1, b1, h11B);                                              \
      h22B = fmaf(u2, b2, h22B);                                              \
      h12B = fmaf(u1, b2, h12B);                                              \
    }                                                                         \
    /* vertical ring update: slot sl holds output row with y%11==sl */        \
    _Pragma("unroll")                                                         \
    for (int sl = 0; sl < 11; ++sl) {                                         \
      const float wt = WG[((P) - sl + 11) % 11];                              \
      acc[sl][0][0]=fmaf(wt,h1A, acc[sl][0][0]); acc[sl][0][1]=fmaf(wt,h1B, acc[sl][0][1]); \
      acc[sl][1][0]=fmaf(wt,h2A, acc[sl][1][0]); acc[sl][1][1]=fmaf(wt,h2B, acc[sl][1][1]); \
      acc[sl][2][0]=fmaf(wt,h11A,acc[sl][2][0]); acc[sl][2][1]=fmaf(wt,h11B,acc[sl][2][1]); \
      acc[sl][3][0]=fmaf(wt,h22A,acc[sl][3][0]); acc[sl][3][1]=fmaf(wt,h22B,acc[sl][3][1]); \
      acc[sl][4][0]=fmaf(wt,h12A,acc[sl][4][0]); acc[sl][4][1]=fmaf(wt,h12B,acc[sl][4][1]); \
    }                                                                         \
    /* slot sc just received its w[10] tap -> output row y completes */       \
    const int sc = ((P) + 1) % 11;                                            \
    const int y = it - 10;                                                    \
    if (it >= 10 && (y0 + y) < OUT_H) {                                       \
      _Pragma("unroll")                                                       \
      for (int s = 0; s < 2; ++s) {                                           \
        if (s == 0 ? validA : validB) {                                       \
          float m1 = acc[sc][0][s], m2 = acc[sc][1][s];                       \
          float mu1s = m1 * m1, mu2s = m2 * m2, mu12 = m1 * m2;               \
          float vA = 2.f * (acc[sc][4][s] - mu12) + SSIM_C2;                  \
          float vB = (acc[sc][2][s] - mu1s) + (acc[sc][3][s] - mu2s) + SSIM_C2; \
          float num = (2.f * mu12 + SSIM_C1) * vA;                            \
          float den = (mu1s + mu2s + SSIM_C1) * vB;                           \
          lsum = fmaf(num, __builtin_amdgcn_rcpf(den), lsum);                 \
        }                                                                     \
      }                                                                       \
    }                                                                         \
    _Pragma("unroll")                                                         \
    for (int ch = 0; ch < 5; ++ch) { acc[sc][ch][0] = 0.f; acc[sc][ch][1] = 0.f; } \
    c1 = n1; c2 = n2;                                                         \
  }

__global__ __launch_bounds__(64, 3) void ssim_main(
    const float* __restrict__ img1,
    const float* __restrict__ img2,
    float* __restrict__ partials)
{
    const int lane   = threadIdx.x;
    const int stripe = blockIdx.x;
    const int cy     = blockIdx.y;
    const int b      = blockIdx.z;
    const int x0 = SW * stripe;
    const int y0 = RCH * cy;

    const float* __restrict__ p1 = img1 + (size_t)b * (IMG_H * IMG_W);
    const float* __restrict__ p2 = img2 + (size_t)b * (IMG_H * IMG_W);

    // lane owns input cols (x0+2l, x0+2l+1); clamp keeps 8B alignment
    int colA = x0 + 2 * lane;  if (colA > IMG_W - 2) colA = IMG_W - 2;
    const int baddr = lane << 2;

    const bool validA = (lane < 59) && (x0 + 2 * lane     < OUT_W);
    const bool validB = (lane < 59) && (x0 + 2 * lane + 1 < OUT_W);

    float acc[11][5][2];
#pragma unroll
    for (int i = 0; i < 11; ++i)
#pragma unroll
        for (int j = 0; j < 5; ++j) { acc[i][j][0] = 0.f; acc[i][j][1] = 0.f; }

    float lsum = 0.f;

    // load row 0
    float2 c1, c2;
    {
        c1 = *(const float2*)(p1 + y0 * IMG_W + colA);
        c2 = *(const float2*)(p2 + y0 * IMG_W + colA);
    }

    // 40 input rows: 3 full 11-phase blocks + 7 tail phases
    for (int blk = 0; blk < 3; ++blk) {
        const int base = blk * 11;
#pragma unroll
        for (int p = 0; p < 11; ++p) PHASE(p, base + p)
    }
    {
        const int base = 33;
#pragma unroll
        for (int p = 0; p < 7; ++p) PHASE(p, base + p)
    }

    // wave-level reduction (64 lanes)
#pragma unroll
    for (int off = 32; off > 0; off >>= 1)
        lsum += __shfl_down(lsum, off);
    if (lane == 0)
        partials[(b * NCHUNK + cy) * NSTRIPE + stripe] = lsum;
}

__global__ __launch_bounds__(256) void ssim_reduce(
    const float* __restrict__ partials, float* __restrict__ out)
{
    const int n = NSTRIPE * NCHUNK * NBATCH;  // 3072
    __shared__ double red[256];
    int tid = threadIdx.x;
    double s = 0.0;
    for (int i = tid; i < n; i += 256) s += (double)partials[i];
    red[tid] = s;
    __syncthreads();
    for (int k = 128; k > 0; k >>= 1) {
        if (tid < k) red[tid] += red[tid + k];
        __syncthreads();
    }
    if (tid == 0) {
        double mean = red[0] / (double)((size_t)NBATCH * OUT_H * OUT_W);
        out[0] = (float)((1.0 - mean) * 0.5);
    }
}

extern "C" void kernel_launch(void* const* d_in, const int* in_sizes, int n_in,
                              void* d_out, int out_size, void* d_ws, size_t ws_size,
                              hipStream_t stream)
{
    const float* img1 = (const float*)d_in[0];
    const float* img2 = (const float*)d_in[1];
    float* out = (float*)d_out;
    float* partials = (float*)d_ws;  // 3072 floats = 12.3 KB

    dim3 grid(NSTRIPE, NCHUNK, NBATCH);  // 6 x 16 x 32 = 3072 single-wave blocks
    ssim_main<<<grid, dim3(64), 0, stream>>>(img1, img2, partials);
    ssim_reduce<<<1, dim3(256), 0, stream>>>(partials, out);
}

// Round 8
// 140.103 us; speedup vs baseline: 1.3494x; 1.3494x over previous
//
#include <hip/hip_runtime.h>

#define IMG_H 480
#define IMG_W 640
#define OUT_H 470    // 480 - 10
#define OUT_W 630    // 640 - 10
#define NBATCH 32
#define SW 118       // output columns per wave (128 input cols - 10 halo)
#define NSTRIPE 6    // ceil(630 / 118)
#define RCH 47       // output rows per wave-chunk (47 * 10 = 470 exact)
#define NCHUNK 10
#define NROWS (RCH + 10)   // 57 input rows per chunk

#define SSIM_C1 1.0f // (0.01*100)^2
#define SSIM_C2 9.0f // (0.03*100)^2

// Normalized 11-tap Gaussian (sigma=1.5), matches numpy fp32 window to ~1e-7 rel.
__device__ constexpr float WG[11] = {
    0.00102838f, 0.00759876f, 0.03600077f, 0.10936068f, 0.21300554f,
    0.26601173f,
    0.21300554f, 0.10936068f, 0.03600077f, 0.00759876f, 0.00102838f
};

// lane+j neighbor fetch via ds_bpermute (register crossbar, no LDS storage,
// no barriers). Wrap for lane+j>63 returns in-wave data (finite), masked by
// the validity predicates.
__device__ __forceinline__ float lane_shift(int baddr, int j, float v) {
    return __int_as_float(
        __builtin_amdgcn_ds_bpermute(baddr + (j << 2), __float_as_int(v)));
}

// One phase of the 11-deep vertical ring, 2 output columns per lane.
// P must be compile-time so acc[] indices and weight selects fold; it ≡ P (mod 11).
// REGISTER BUDGET (R4/R5/R7 lesson): live set ≈ 110-reg ring + ~75 working.
// gfx950 unified VGPR/AGPR pool ~512/wave: __launch_bounds__(64,2) -> 256-reg
// cap (fits). (64,3)'s 170-reg cap SPILLED the ring (R7: WRITE_SIZE 36.7 MB).
// Sentinel: WRITE_SIZE must stay ~0.2 MB.
#define PHASE(P, IT)                                                          \
  {                                                                           \
    const int it = (IT);                                                      \
    /* prefetch next input row (coalesced float2) to hide VMEM latency */     \
    float2 n1 = make_float2(0.f, 0.f), n2 = n1;                               \
    if (it + 1 < NROWS) {                                                     \
      int gy = y0 + it + 1; if (gy > IMG_H - 1) gy = IMG_H - 1;               \
      n1 = *(const float2*)(p1 + gy * IMG_W + colA);                          \
      n2 = *(const float2*)(p2 + gy * IMG_W + colA);                          \
    }                                                                         \
    /* gather cols 2l..2l+11 (pairs from lanes l..l+5): 20 bpermutes */       \
    float v1[12], v2[12];                                                     \
    v1[0] = c1.x; v1[1] = c1.y; v2[0] = c2.x; v2[1] = c2.y;                   \
    _Pragma("unroll")                                                         \
    for (int j = 1; j <= 5; ++j) {                                            \
      v1[2*j]   = lane_shift(baddr, j, c1.x);                                 \
      v1[2*j+1] = lane_shift(baddr, j, c1.y);                                 \
      v2[2*j]   = lane_shift(baddr, j, c2.x);                                 \
      v2[2*j+1] = lane_shift(baddr, j, c2.y);                                 \
    }                                                                         \
    /* horizontal 11-tap pass, 5 channels, two outputs (A: v[0..10], B: v[1..11]) */ \
    float h1A=0.f,h2A=0.f,h11A=0.f,h22A=0.f,h12A=0.f;                         \
    float h1B=0.f,h2B=0.f,h11B=0.f,h22B=0.f,h12B=0.f;                         \
    _Pragma("unroll")                                                         \
    for (int j = 0; j < 11; ++j) {                                            \
      float a1 = v1[j], a2 = v2[j];                                           \
      float t1 = WG[j] * a1, t2 = WG[j] * a2;                                 \
      h1A += t1; h2A += t2;                                                   \
      h11A = fmaf(t1, a1, h11A);                                              \
      h22A = fmaf(t2, a2, h22A);                                              \
      h12A = fmaf(t1, a2, h12A);                                              \
      float b1 = v1[j+1], b2 = v2[j+1];                                       \
      float u1 = WG[j] * b1, u2 = WG[j] * b2;                                 \
      h1B += u1; h2B += u2;                                                   \
      h11B = fmaf(u1, b1, h11B);                                              \
      h22B = fmaf(u2, b2, h22B);                                              \
      h12B = fmaf(u1, b2, h12B);                                              \
    }                                                                         \
    /* vertical ring update: slot sl holds output row with y%11==sl */        \
    _Pragma("unroll")                                                         \
    for (int sl = 0; sl < 11; ++sl) {                                         \
      const float wt = WG[((P) - sl + 11) % 11];                              \
      acc[sl][0][0]=fmaf(wt,h1A, acc[sl][0][0]); acc[sl][0][1]=fmaf(wt,h1B, acc[sl][0][1]); \
      acc[sl][1][0]=fmaf(wt,h2A, acc[sl][1][0]); acc[sl][1][1]=fmaf(wt,h2B, acc[sl][1][1]); \
      acc[sl][2][0]=fmaf(wt,h11A,acc[sl][2][0]); acc[sl][2][1]=fmaf(wt,h11B,acc[sl][2][1]); \
      acc[sl][3][0]=fmaf(wt,h22A,acc[sl][3][0]); acc[sl][3][1]=fmaf(wt,h22B,acc[sl][3][1]); \
      acc[sl][4][0]=fmaf(wt,h12A,acc[sl][4][0]); acc[sl][4][1]=fmaf(wt,h12B,acc[sl][4][1]); \
    }                                                                         \
    /* slot sc just received its w[10] tap -> output row y completes */       \
    const int sc = ((P) + 1) % 11;                                            \
    const int y = it - 10;                                                    \
    if (it >= 10 && (y0 + y) < OUT_H) {                                       \
      _Pragma("unroll")                                                       \
      for (int s = 0; s < 2; ++s) {                                           \
        if (s == 0 ? validA : validB) {                                       \
          float m1 = acc[sc][0][s], m2 = acc[sc][1][s];                       \
          float mu1s = m1 * m1, mu2s = m2 * m2, mu12 = m1 * m2;               \
          float vA = 2.f * (acc[sc][4][s] - mu12) + SSIM_C2;                  \
          float vB = (acc[sc][2][s] - mu1s) + (acc[sc][3][s] - mu2s) + SSIM_C2; \
          float num = (2.f * mu12 + SSIM_C1) * vA;                            \
          float den = (mu1s + mu2s + SSIM_C1) * vB;                           \
          lsum = fmaf(num, __builtin_amdgcn_rcpf(den), lsum);                 \
        }                                                                     \
      }                                                                       \
    }                                                                         \
    _Pragma("unroll")                                                         \
    for (int ch = 0; ch < 5; ++ch) { acc[sc][ch][0] = 0.f; acc[sc][ch][1] = 0.f; } \
    c1 = n1; c2 = n2;                                                         \
  }

__global__ __launch_bounds__(64, 2) void ssim_main(
    const float* __restrict__ img1,
    const float* __restrict__ img2,
    float* __restrict__ partials)
{
    const int lane   = threadIdx.x;
    const int stripe = blockIdx.x;
    const int cy     = blockIdx.y;
    const int b      = blockIdx.z;
    const int x0 = SW * stripe;
    const int y0 = RCH * cy;

    const float* __restrict__ p1 = img1 + (size_t)b * (IMG_H * IMG_W);
    const float* __restrict__ p2 = img2 + (size_t)b * (IMG_H * IMG_W);

    // lane owns input cols (x0+2l, x0+2l+1); clamp keeps 8B alignment
    int colA = x0 + 2 * lane;  if (colA > IMG_W - 2) colA = IMG_W - 2;
    const int baddr = lane << 2;

    // lane l consumes input cols 2l..2l+11 -> lanes 0..58 produce valid outputs
    const bool validA = (lane < 59) && (x0 + 2 * lane     < OUT_W);
    const bool validB = (lane < 59) && (x0 + 2 * lane + 1 < OUT_W);

    float acc[11][5][2];
#pragma unroll
    for (int i = 0; i < 11; ++i)
#pragma unroll
        for (int j = 0; j < 5; ++j) { acc[i][j][0] = 0.f; acc[i][j][1] = 0.f; }

    float lsum = 0.f;

    // load row 0
    float2 c1, c2;
    {
        c1 = *(const float2*)(p1 + y0 * IMG_W + colA);
        c2 = *(const float2*)(p2 + y0 * IMG_W + colA);
    }

    // 57 input rows: 5 full 11-phase blocks + 2 tail phases
    for (int blk = 0; blk < 5; ++blk) {
        const int base = blk * 11;
#pragma unroll
        for (int p = 0; p < 11; ++p) PHASE(p, base + p)
    }
    {
        const int base = 55;
#pragma unroll
        for (int p = 0; p < 2; ++p) PHASE(p, base + p)
    }

    // wave-level reduction (64 lanes)
#pragma unroll
    for (int off = 32; off > 0; off >>= 1)
        lsum += __shfl_down(lsum, off);
    if (lane == 0)
        partials[(b * NCHUNK + cy) * NSTRIPE + stripe] = lsum;
}

__global__ __launch_bounds__(256) void ssim_reduce(
    const float* __restrict__ partials, float* __restrict__ out)
{
    const int n = NSTRIPE * NCHUNK * NBATCH;  // 1920
    __shared__ double red[256];
    int tid = threadIdx.x;
    double s = 0.0;
    for (int i = tid; i < n; i += 256) s += (double)partials[i];
    red[tid] = s;
    __syncthreads();
    for (int k = 128; k > 0; k >>= 1) {
        if (tid < k) red[tid] += red[tid + k];
        __syncthreads();
    }
    if (tid == 0) {
        double mean = red[0] / (double)((size_t)NBATCH * OUT_H * OUT_W);
        out[0] = (float)((1.0 - mean) * 0.5);
    }
}

extern "C" void kernel_launch(void* const* d_in, const int* in_sizes, int n_in,
                              void* d_out, int out_size, void* d_ws, size_t ws_size,
                              hipStream_t stream)
{
    const float* img1 = (const float*)d_in[0];
    const float* img2 = (const float*)d_in[1];
    float* out = (float*)d_out;
    float* partials = (float*)d_ws;  // 1920 floats = 7.7 KB

    dim3 grid(NSTRIPE, NCHUNK, NBATCH);  // 6 x 10 x 32 = 1920 single-wave blocks
    ssim_main<<<grid, dim3(64), 0, stream>>>(img1, img2, partials);
    ssim_reduce<<<1, dim3(256), 0, stream>>>(partials, out);
}

// Round 9
// 136.536 us; speedup vs baseline: 1.3846x; 1.0261x over previous
//
#include <hip/hip_runtime.h>

#define IMG_H 480
#define IMG_W 640
#define OUT_H 470    // 480 - 10
#define OUT_W 630    // 640 - 10
#define NBATCH 32
#define SW 118       // output columns per wave (128 input cols - 10 halo)
#define NSTRIPE 6    // ceil(630 / 118)
#define RCH 47       // output rows per wave-chunk (47 * 10 = 470 exact)
#define NCHUNK 10
#define NROWS (RCH + 10)   // 57 input rows per chunk

#define SSIM_C1 1.0f // (0.01*100)^2
#define SSIM_C2 9.0f // (0.03*100)^2

typedef float v2f __attribute__((ext_vector_type(2)));

// Normalized 11-tap Gaussian (sigma=1.5), matches numpy fp32 window to ~1e-7 rel.
__device__ constexpr float WG[11] = {
    0.00102838f, 0.00759876f, 0.03600077f, 0.10936068f, 0.21300554f,
    0.26601173f,
    0.21300554f, 0.10936068f, 0.03600077f, 0.00759876f, 0.00102838f
};

// lane+j neighbor fetch via ds_bpermute (register crossbar, no LDS storage,
// no barriers). Wrap for lane+j>63 returns in-wave data (finite), masked by
// the validity predicates.
__device__ __forceinline__ float lane_shift(int baddr, int j, float v) {
    return __int_as_float(
        __builtin_amdgcn_ds_bpermute(baddr + (j << 2), __float_as_int(v)));
}

// Packed fp32 fma: llvm.fma.v2f32 -> v_pk_fma_f32 (2 FLOP-pairs per issue slot)
__device__ __forceinline__ v2f pk_fma(v2f a, v2f b, v2f c) {
    return __builtin_elementwise_fma(a, b, c);
}

// One phase of the 11-deep vertical ring, 2 output columns per lane, math
// packed over (img1,img2) so the backend emits v_pk_{mul,add,fma}_f32.
// P must be compile-time so acc[] indices and weight selects fold; it ≡ P (mod 11).
// REGISTER BUDGET (R4/R5/R7 lesson): live set ≈ 110-reg ring + ~80 working.
// gfx950 unified VGPR/AGPR pool ~512/wave: __launch_bounds__(64,2) -> 256-reg
// cap (fits). waves/EU=3 (170-reg cap) SPILLED (R7: WRITE_SIZE 36.7 MB).
// Sentinel: WRITE_SIZE must stay ~0.06 MB.
#define PHASE(P, IT)                                                          \
  {                                                                           \
    const int it = (IT);                                                      \
    /* prefetch next input row (clamped, branch-free) to hide VMEM latency */ \
    int gy = y0 + it + 1; if (gy > IMG_H - 1) gy = IMG_H - 1;                 \
    const float2 n1 = *(const float2*)(p1 + gy * IMG_W + colA);               \
    const float2 n2 = *(const float2*)(p2 + gy * IMG_W + colA);               \
    /* gather cols 2l..2l+11, packed (img1,img2): 20 bpermutes */             \
    v2f pv[12];                                                               \
    pv[0].x = c1.x; pv[0].y = c2.x;                                           \
    pv[1].x = c1.y; pv[1].y = c2.y;                                           \
    _Pragma("unroll")                                                         \
    for (int j = 1; j <= 5; ++j) {                                            \
      pv[2*j].x   = lane_shift(baddr, j, c1.x);                               \
      pv[2*j].y   = lane_shift(baddr, j, c2.x);                               \
      pv[2*j+1].x = lane_shift(baddr, j, c1.y);                               \
      pv[2*j+1].y = lane_shift(baddr, j, c2.y);                               \
    }                                                                         \
    /* horizontal 11-tap pass, packed: per tap per col = 3 pk + 1 scalar */   \
    v2f ph[2], phs[2]; float ph12[2];                                         \
    ph[0] = (v2f){0.f,0.f}; ph[1] = (v2f){0.f,0.f};                           \
    phs[0] = (v2f){0.f,0.f}; phs[1] = (v2f){0.f,0.f};                         \
    ph12[0] = 0.f; ph12[1] = 0.f;                                             \
    _Pragma("unroll")                                                         \
    for (int j = 0; j < 11; ++j) {                                            \
      const v2f wj = (v2f){WG[j], WG[j]};                                     \
      _Pragma("unroll")                                                       \
      for (int s = 0; s < 2; ++s) {                                           \
        const v2f v = pv[j + s];                                              \
        const v2f t = wj * v;            /* pk_mul: (w*v1, w*v2) */           \
        ph[s] += t;                      /* pk_add: (h1, h2)     */           \
        phs[s] = pk_fma(t, v, phs[s]);   /* pk_fma: (h11, h22)   */           \
        ph12[s] = fmaf(t.x, v.y, ph12[s]); /* scalar: h12        */           \
      }                                                                       \
    }                                                                         \
    /* vertical ring update: per slot per col = 2 pk_fma + 1 fma */           \
    _Pragma("unroll")                                                         \
    for (int sl = 0; sl < 11; ++sl) {                                         \
      const float wt = WG[((P) - sl + 11) % 11];                              \
      const v2f wv = (v2f){wt, wt};                                           \
      _Pragma("unroll")                                                       \
      for (int s = 0; s < 2; ++s) {                                           \
        acc_mu[sl][s] = pk_fma(wv, ph[s],  acc_mu[sl][s]);                    \
        acc_sq[sl][s] = pk_fma(wv, phs[s], acc_sq[sl][s]);                    \
        acc_x[sl][s]  = fmaf(wt, ph12[s],  acc_x[sl][s]);                     \
      }                                                                       \
    }                                                                         \
    /* slot sc just received its w[10] tap -> output row y completes */       \
    const int sc = ((P) + 1) % 11;                                            \
    const int y = it - 10;                                                    \
    if (it >= 10 && (y0 + y) < OUT_H) {                                       \
      _Pragma("unroll")                                                       \
      for (int s = 0; s < 2; ++s) {                                           \
        if (s == 0 ? validA : validB) {                                       \
          const v2f m = acc_mu[sc][s];        /* (mu1, mu2) */                \
          const v2f msq = m * m;              /* (mu1^2, mu2^2) */            \
          const float mu12 = m.x * m.y;                                       \
          const v2f sg = acc_sq[sc][s] - msq; /* (sg1, sg2) */                \
          const float vA = fmaf(2.f, acc_x[sc][s] - mu12, SSIM_C2);           \
          const float vB = sg.x + sg.y + SSIM_C2;                             \
          const float num = fmaf(2.f, mu12, SSIM_C1) * vA;                    \
          const float den = (msq.x + msq.y + SSIM_C1) * vB;                   \
          lsum = fmaf(num, __builtin_amdgcn_rcpf(den), lsum);                 \
        }                                                                     \
      }                                                                       \
    }                                                                         \
    _Pragma("unroll")                                                         \
    for (int s = 0; s < 2; ++s) {                                             \
      acc_mu[sc][s] = (v2f){0.f,0.f};                                         \
      acc_sq[sc][s] = (v2f){0.f,0.f};                                         \
      acc_x[sc][s]  = 0.f;                                                    \
    }                                                                         \
    c1 = n1; c2 = n2;                                                         \
  }

__global__ __launch_bounds__(64, 2) void ssim_main(
    const float* __restrict__ img1,
    const float* __restrict__ img2,
    float* __restrict__ partials)
{
    const int lane   = threadIdx.x;
    const int stripe = blockIdx.x;
    const int cy     = blockIdx.y;
    const int b      = blockIdx.z;
    const int x0 = SW * stripe;
    const int y0 = RCH * cy;

    const float* __restrict__ p1 = img1 + (size_t)b * (IMG_H * IMG_W);
    const float* __restrict__ p2 = img2 + (size_t)b * (IMG_H * IMG_W);

    // lane owns input cols (x0+2l, x0+2l+1); clamp keeps 8B alignment
    int colA = x0 + 2 * lane;  if (colA > IMG_W - 2) colA = IMG_W - 2;
    const int baddr = lane << 2;

    // lane l consumes input cols 2l..2l+11 -> lanes 0..58 produce valid outputs
    const bool validA = (lane < 59) && (x0 + 2 * lane     < OUT_W);
    const bool validB = (lane < 59) && (x0 + 2 * lane + 1 < OUT_W);

    // vertical ring: (mu1,mu2) pk, (s11,s22) pk, s12 scalar, per 2 cols
    v2f acc_mu[11][2], acc_sq[11][2];
    float acc_x[11][2];
#pragma unroll
    for (int i = 0; i < 11; ++i)
#pragma unroll
        for (int s = 0; s < 2; ++s) {
            acc_mu[i][s] = (v2f){0.f, 0.f};
            acc_sq[i][s] = (v2f){0.f, 0.f};
            acc_x[i][s] = 0.f;
        }

    float lsum = 0.f;

    // load row 0
    float2 c1 = *(const float2*)(p1 + y0 * IMG_W + colA);
    float2 c2 = *(const float2*)(p2 + y0 * IMG_W + colA);

    // 57 input rows: 5 full 11-phase blocks + 2 tail phases
    for (int blk = 0; blk < 5; ++blk) {
        const int base = blk * 11;
#pragma unroll
        for (int p = 0; p < 11; ++p) PHASE(p, base + p)
    }
    {
        const int base = 55;
#pragma unroll
        for (int p = 0; p < 2; ++p) PHASE(p, base + p)
    }

    // wave-level reduction (64 lanes)
#pragma unroll
    for (int off = 32; off > 0; off >>= 1)
        lsum += __shfl_down(lsum, off);
    if (lane == 0)
        partials[(b * NCHUNK + cy) * NSTRIPE + stripe] = lsum;
}

__global__ __launch_bounds__(256) void ssim_reduce(
    const float* __restrict__ partials, float* __restrict__ out)
{
    const int n = NSTRIPE * NCHUNK * NBATCH;  // 1920
    __shared__ double red[256];
    int tid = threadIdx.x;
    double s = 0.0;
    for (int i = tid; i < n; i += 256) s += (double)partials[i];
    red[tid] = s;
    __syncthreads();
    for (int k = 128; k > 0; k >>= 1) {
        if (tid < k) red[tid] += red[tid + k];
        __syncthreads();
    }
    if (tid == 0) {
        double mean = red[0] / (double)((size_t)NBATCH * OUT_H * OUT_W);
        out[0] = (float)((1.0 - mean) * 0.5);
    }
}

extern "C" void kernel_launch(void* const* d_in, const int* in_sizes, int n_in,
                              void* d_out, int out_size, void* d_ws, size_t ws_size,
                              hipStream_t stream)
{
    const float* img1 = (const float*)d_in[0];
    const float* img2 = (const float*)d_in[1];
    float* out = (float*)d_out;
    float* partials = (float*)d_ws;  // 1920 floats = 7.7 KB

    dim3 grid(NSTRIPE, NCHUNK, NBATCH);  // 6 x 10 x 32 = 1920 single-wave blocks
    ssim_main<<<grid, dim3(64), 0, stream>>>(img1, img2, partials);
    ssim_reduce<<<1, dim3(256), 0, stream>>>(partials, out);
}